// Round 3
// baseline (2178.479 us; speedup 1.0000x reference)
//
#include <hip/hip_runtime.h>

namespace {

constexpr int DIMC  = 1024;
constexpr int HEADS = 16;
constexpr int HD    = 64;
constexpr int BATCH = 4;
constexpr int SEQ   = 2048;
constexpr float SCALE = 0.125f;   // 1/sqrt(64)

// ---------------------------------------------------------------------------
// Generic GEMM: C[M,N] = A[M,K] @ W[N,K]^T + bias[N]
// BM=BN=128, BK=16, 256 threads, 8x8 microtile per thread.
// ---------------------------------------------------------------------------
constexpr int BM = 128, BN = 128, BK = 16;

__global__ __launch_bounds__(256) void gemm_bias_kernel(
    const float* __restrict__ A, const float* __restrict__ W,
    const float* __restrict__ bias, float* __restrict__ C,
    int M, int N, int K)
{
    __shared__ float As[BK][BM + 4];   // stored transposed: As[k][m]
    __shared__ float Ws[BK][BN + 4];

    const int tid  = threadIdx.x;
    const int tx   = tid & 15;          // 16 thread cols
    const int ty   = tid >> 4;          // 16 thread rows
    const int row0 = blockIdx.y * BM;
    const int col0 = blockIdx.x * BN;

    const int lr = tid >> 2;            // 0..63  (load row)
    const int lk = (tid & 3) * 4;       // 0,4,8,12 (load k)

    float acc[8][8];
#pragma unroll
    for (int i = 0; i < 8; ++i)
#pragma unroll
        for (int j = 0; j < 8; ++j) acc[i][j] = 0.f;

    const float* Arow0 = A + (size_t)(row0 + lr) * K + lk;
    const float* Arow1 = A + (size_t)(row0 + lr + 64) * K + lk;
    const float* Wrow0 = W + (size_t)(col0 + lr) * K + lk;
    const float* Wrow1 = W + (size_t)(col0 + lr + 64) * K + lk;

    for (int k0 = 0; k0 < K; k0 += BK) {
        const float4 a0 = *(const float4*)(Arow0 + k0);
        const float4 a1 = *(const float4*)(Arow1 + k0);
        const float4 w0 = *(const float4*)(Wrow0 + k0);
        const float4 w1 = *(const float4*)(Wrow1 + k0);

        __syncthreads();   // previous iteration's compute done
        As[lk + 0][lr]      = a0.x; As[lk + 1][lr]      = a0.y;
        As[lk + 2][lr]      = a0.z; As[lk + 3][lr]      = a0.w;
        As[lk + 0][lr + 64] = a1.x; As[lk + 1][lr + 64] = a1.y;
        As[lk + 2][lr + 64] = a1.z; As[lk + 3][lr + 64] = a1.w;
        Ws[lk + 0][lr]      = w0.x; Ws[lk + 1][lr]      = w0.y;
        Ws[lk + 2][lr]      = w0.z; Ws[lk + 3][lr]      = w0.w;
        Ws[lk + 0][lr + 64] = w1.x; Ws[lk + 1][lr + 64] = w1.y;
        Ws[lk + 2][lr + 64] = w1.z; Ws[lk + 3][lr + 64] = w1.w;
        __syncthreads();

#pragma unroll
        for (int k = 0; k < BK; ++k) {
            float a[8], b[8];
            *(float4*)&a[0] = *(const float4*)&As[k][ty * 8];
            *(float4*)&a[4] = *(const float4*)&As[k][ty * 8 + 4];
            *(float4*)&b[0] = *(const float4*)&Ws[k][tx * 8];
            *(float4*)&b[4] = *(const float4*)&Ws[k][tx * 8 + 4];
#pragma unroll
            for (int i = 0; i < 8; ++i)
#pragma unroll
                for (int j = 0; j < 8; ++j)
                    acc[i][j] += a[i] * b[j];
        }
    }

    // epilogue: add bias, store
    float bv[8];
#pragma unroll
    for (int j = 0; j < 8; ++j) bv[j] = bias[col0 + tx * 8 + j];
#pragma unroll
    for (int i = 0; i < 8; ++i) {
        float* crow = C + (size_t)(row0 + ty * 8 + i) * N + col0 + tx * 8;
        float4 r0 = make_float4(acc[i][0] + bv[0], acc[i][1] + bv[1],
                                acc[i][2] + bv[2], acc[i][3] + bv[3]);
        float4 r1 = make_float4(acc[i][4] + bv[4], acc[i][5] + bv[5],
                                acc[i][6] + bv[6], acc[i][7] + bv[7]);
        *(float4*)(crow)     = r0;
        *(float4*)(crow + 4) = r1;
    }
}

// ---------------------------------------------------------------------------
// Flash attention (fp32, vector ALU). One workgroup = 64 q-rows of one (b,h).
// qkv layout: [B, S, 3, HEADS, HD]  (row stride 3*DIMC floats)
// ctx layout: [B, S, HEADS, HD] == [B, S, DIMC]
// ---------------------------------------------------------------------------
__global__ __launch_bounds__(256) void attn_kernel(
    const float* __restrict__ qkv, float* __restrict__ ctx)
{
    constexpr int QT = 64, KT = 32;
    constexpr int QS = HD + 4;      // 68: float4-aligned rows, spread banks
    constexpr int PS = KT + 4;      // 36

    __shared__ float Qs[QT][QS];
    __shared__ float Ks[KT][QS];
    __shared__ float Vs[KT][HD];
    __shared__ float Ps[QT][PS];
    __shared__ float corr_s[QT];
    __shared__ float l_s[QT];

    const int b  = blockIdx.z;
    const int h  = blockIdx.y;
    const int q0 = blockIdx.x * QT;
    const int tid = threadIdx.x;

    const size_t rowstride = (size_t)3 * DIMC;
    const float* qbase = qkv + (size_t)b * SEQ * rowstride + (size_t)h * HD;
    const float* kbase = qbase + DIMC;
    const float* vbase = qbase + 2 * DIMC;

    // ---- load Q tile ----
    {
        const int r = tid >> 2;
        const int c = (tid & 3) * 16;
        const float* src = qbase + (size_t)(q0 + r) * rowstride + c;
        float4 v0 = *(const float4*)(src);
        float4 v1 = *(const float4*)(src + 4);
        float4 v2 = *(const float4*)(src + 8);
        float4 v3 = *(const float4*)(src + 12);
        *(float4*)&Qs[r][c]      = v0;
        *(float4*)&Qs[r][c + 4]  = v1;
        *(float4*)&Qs[r][c + 8]  = v2;
        *(float4*)&Qs[r][c + 12] = v3;
    }

    const int i0 = tid >> 3;            // 0..31 : rows {i0, i0+32}
    const int j0 = (tid & 7) * 4;       // S-cols
    const int c0 = (tid & 7) * 8;       // O-cols

    const int lrow = tid >> 3;          // 0..31 (K/V load row)
    const int lcol = (tid & 7) * 8;

    float o[2][8];
#pragma unroll
    for (int c = 0; c < 8; ++c) { o[0][c] = 0.f; o[1][c] = 0.f; }

    float m_run = -3.4e38f;   // per softmax thread (tid<64 owns row tid)
    float l_run = 0.f;

    for (int kv0 = 0; kv0 < SEQ; kv0 += KT) {
        // global loads first (overlap with previous tile's compute)
        const float* ksrc = kbase + (size_t)(kv0 + lrow) * rowstride + lcol;
        const float* vsrc = vbase + (size_t)(kv0 + lrow) * rowstride + lcol;
        const float4 kl0 = *(const float4*)(ksrc);
        const float4 kl1 = *(const float4*)(ksrc + 4);
        const float4 vl0 = *(const float4*)(vsrc);
        const float4 vl1 = *(const float4*)(vsrc + 4);

        __syncthreads();   // [A] previous compute done (Ps/Vs/Ks free)
        *(float4*)&Ks[lrow][lcol]     = kl0;
        *(float4*)&Ks[lrow][lcol + 4] = kl1;
        *(float4*)&Vs[lrow][lcol]     = vl0;
        *(float4*)&Vs[lrow][lcol + 4] = vl1;
        __syncthreads();   // [B] tiles visible

        // ---- S = Q K^T (raw, scale applied in softmax) ----
        float s0[4] = {0.f, 0.f, 0.f, 0.f};
        float s1[4] = {0.f, 0.f, 0.f, 0.f};
#pragma unroll
        for (int k = 0; k < HD; k += 4) {
            const float4 qa = *(const float4*)&Qs[i0][k];
            const float4 qb = *(const float4*)&Qs[i0 + 32][k];
#pragma unroll
            for (int jj = 0; jj < 4; ++jj) {
                const float4 kv = *(const float4*)&Ks[j0 + jj][k];
                s0[jj] += qa.x * kv.x + qa.y * kv.y + qa.z * kv.z + qa.w * kv.w;
                s1[jj] += qb.x * kv.x + qb.y * kv.y + qb.z * kv.z + qb.w * kv.w;
            }
        }
        *(float4*)&Ps[i0][j0]      = make_float4(s0[0], s0[1], s0[2], s0[3]);
        *(float4*)&Ps[i0 + 32][j0] = make_float4(s1[0], s1[1], s1[2], s1[3]);
        __syncthreads();   // [C] scores visible

        // ---- online softmax: thread r (<64) owns row r ----
        if (tid < QT) {
            float vals[KT];
            float mx = m_run;
#pragma unroll
            for (int j = 0; j < KT; ++j) {
                const float v = Ps[tid][j] * SCALE;
                vals[j] = v;
                mx = fmaxf(mx, v);
            }
            const float corr = __expf(m_run - mx);
            float sum = 0.f;
#pragma unroll
            for (int j = 0; j < KT; ++j) {
                const float p = __expf(vals[j] - mx);
                Ps[tid][j] = p;
                sum += p;
            }
            l_run = l_run * corr + sum;
            m_run = mx;
            corr_s[tid] = corr;
        }
        __syncthreads();   // [D] probs + corr visible

        // ---- O = O*corr + P V ----
        const float corr0 = corr_s[i0];
        const float corr1 = corr_s[i0 + 32];
#pragma unroll
        for (int c = 0; c < 8; ++c) { o[0][c] *= corr0; o[1][c] *= corr1; }
#pragma unroll
        for (int j = 0; j < KT; ++j) {
            const float p0 = Ps[i0][j];
            const float p1 = Ps[i0 + 32][j];
            const float4 va = *(const float4*)&Vs[j][c0];
            const float4 vb = *(const float4*)&Vs[j][c0 + 4];
            o[0][0] += p0 * va.x; o[0][1] += p0 * va.y;
            o[0][2] += p0 * va.z; o[0][3] += p0 * va.w;
            o[0][4] += p0 * vb.x; o[0][5] += p0 * vb.y;
            o[0][6] += p0 * vb.z; o[0][7] += p0 * vb.w;
            o[1][0] += p1 * va.x; o[1][1] += p1 * va.y;
            o[1][2] += p1 * va.z; o[1][3] += p1 * va.w;
            o[1][4] += p1 * vb.x; o[1][5] += p1 * vb.y;
            o[1][6] += p1 * vb.z; o[1][7] += p1 * vb.w;
        }
    }

    if (tid < QT) l_s[tid] = l_run;
    __syncthreads();

    const float inv0 = 1.f / l_s[i0];
    const float inv1 = 1.f / l_s[i0 + 32];
    float* dst0 = ctx + ((size_t)(b * SEQ + q0 + i0)      * DIMC) + h * HD + c0;
    float* dst1 = ctx + ((size_t)(b * SEQ + q0 + i0 + 32) * DIMC) + h * HD + c0;
    *(float4*)(dst0)     = make_float4(o[0][0] * inv0, o[0][1] * inv0,
                                       o[0][2] * inv0, o[0][3] * inv0);
    *(float4*)(dst0 + 4) = make_float4(o[0][4] * inv0, o[0][5] * inv0,
                                       o[0][6] * inv0, o[0][7] * inv0);
    *(float4*)(dst1)     = make_float4(o[1][0] * inv1, o[1][1] * inv1,
                                       o[1][2] * inv1, o[1][3] * inv1);
    *(float4*)(dst1 + 4) = make_float4(o[1][4] * inv1, o[1][5] * inv1,
                                       o[1][6] * inv1, o[1][7] * inv1);
}

} // namespace

extern "C" void kernel_launch(void* const* d_in, const int* in_sizes, int n_in,
                              void* d_out, int out_size, void* d_ws, size_t ws_size,
                              hipStream_t stream)
{
    const float* x     = (const float*)d_in[0];
    const float* qkv_w = (const float*)d_in[1];
    const float* qkv_b = (const float*)d_in[2];
    const float* out_w = (const float*)d_in[3];
    const float* out_b = (const float*)d_in[4];
    float* out = (float*)d_out;

    // workspace: qkv [B,S,3*DIM] then ctx [B,S,DIM]  (134.2 MB total)
    float* qkv = (float*)d_ws;
    float* ctx = qkv + (size_t)BATCH * SEQ * 3 * DIMC;

    const int M = BATCH * SEQ;   // 8192

    // 1) QKV projection: [8192,1024] @ [3072,1024]^T -> [8192,3072]
    gemm_bias_kernel<<<dim3(3 * DIMC / BN, M / BM), dim3(256), 0, stream>>>(
        x, qkv_w, qkv_b, qkv, M, 3 * DIMC, DIMC);

    // 2) flash attention -> ctx [B,S,DIM]
    attn_kernel<<<dim3(SEQ / 64, HEADS, BATCH), dim3(256), 0, stream>>>(qkv, ctx);

    // 3) output projection: [8192,1024] @ [1024,1024]^T -> [8192,1024]
    gemm_bias_kernel<<<dim3(DIMC / BN, M / BM), dim3(256), 0, stream>>>(
        ctx, out_w, out_b, out, M, DIMC, DIMC);
}

// Round 4
// 380.929 us; speedup vs baseline: 5.7189x; 5.7189x over previous
//
#include <hip/hip_runtime.h>

namespace {

constexpr int DIMC  = 1024;
constexpr int HEADS = 16;
constexpr int HD    = 64;
constexpr int BATCH = 4;
constexpr int SEQ   = 2048;
constexpr float SCALE = 0.125f;   // 1/sqrt(64)

typedef __attribute__((ext_vector_type(8))) short short8;   // 8 bf16 (4 VGPRs)
typedef __attribute__((ext_vector_type(4))) float f32x4;

__device__ __forceinline__ unsigned short f2bf(float f) {
    union { float f; unsigned u; } v; v.f = f;
    unsigned r = v.u + 0x7fffu + ((v.u >> 16) & 1u);   // RNE
    return (unsigned short)(r >> 16);
}

// async global->LDS, 16B per lane; ldst must be wave-uniform base (HW adds lane*16)
__device__ __forceinline__ void gl16(const unsigned short* gsrc, const unsigned short* ldst) {
    __builtin_amdgcn_global_load_lds(
        (const __attribute__((address_space(1))) void*)gsrc,
        (__attribute__((address_space(3))) void*)ldst, 16, 0, 0);
}

// ---------------------------------------------------------------------------
// fp32 -> bf16 elementwise (8 elems/thread/iter)
// ---------------------------------------------------------------------------
__global__ __launch_bounds__(256) void cvt_f32_bf16(
    const float* __restrict__ in, unsigned short* __restrict__ out, int n8)
{
    for (int i = blockIdx.x * blockDim.x + threadIdx.x; i < n8;
         i += gridDim.x * blockDim.x) {
        const float4 a = ((const float4*)in)[2*i];
        const float4 b = ((const float4*)in)[2*i + 1];
        union { unsigned short s[8]; uint4 u; } p;
        p.s[0]=f2bf(a.x); p.s[1]=f2bf(a.y); p.s[2]=f2bf(a.z); p.s[3]=f2bf(a.w);
        p.s[4]=f2bf(b.x); p.s[5]=f2bf(b.y); p.s[6]=f2bf(b.z); p.s[7]=f2bf(b.w);
        ((uint4*)out)[i] = p.u;
    }
}

// ---------------------------------------------------------------------------
// bf16 GEMM: C[M,N] = A[M,K] @ W[N,K]^T + bias.  128x128 tile, BK=32,
// 4 waves (2x2), 64x64/wave, mfma_f32_16x16x32_bf16, global_load_lds staging.
// OUT_BF16=1 -> bf16 output, else f32.
// ---------------------------------------------------------------------------
template<int OUT_BF16>
__global__ __launch_bounds__(256) void gemm_bf16_mfma(
    const unsigned short* __restrict__ A, const unsigned short* __restrict__ W,
    const float* __restrict__ bias, void* __restrict__ Cout,
    int M, int N, int K)
{
    __shared__ __align__(16) char lds[17408];         // 16KB tiles / 17KB repack
    unsigned short* Asb = (unsigned short*)lds;       // [128][32]
    unsigned short* Bsb = Asb + 128*32;               // [128][32]

    const int tid = threadIdx.x;
    const int w = tid >> 6, l = tid & 63;
    const int wr = w >> 1, wc = w & 1;
    const int fr = l & 15, fq = l >> 4;
    const int row0 = blockIdx.y * 128, col0 = blockIdx.x * 128;

    // staging: chunk (w,i) covers rows (w*2+i)*16 + l/4, k-col (l&3)*8
    const int sr0 = (w*2 + 0)*16 + (l >> 2);
    const int sr1 = (w*2 + 1)*16 + (l >> 2);
    const int sk  = (l & 3) * 8;

    const unsigned short* Ab0 = A + (size_t)(row0 + sr0)*K + sk;
    const unsigned short* Ab1 = A + (size_t)(row0 + sr1)*K + sk;
    const unsigned short* Wb0 = W + (size_t)(col0 + sr0)*K + sk;
    const unsigned short* Wb1 = W + (size_t)(col0 + sr1)*K + sk;

    const unsigned short* ldsA0 = Asb + (w*2 + 0)*512;   // 1024 B chunks
    const unsigned short* ldsA1 = Asb + (w*2 + 1)*512;
    const unsigned short* ldsB0 = Bsb + (w*2 + 0)*512;
    const unsigned short* ldsB1 = Bsb + (w*2 + 1)*512;

    f32x4 acc[4][4];
#pragma unroll
    for (int mi = 0; mi < 4; ++mi)
#pragma unroll
        for (int ni = 0; ni < 4; ++ni)
#pragma unroll
            for (int r = 0; r < 4; ++r) acc[mi][ni][r] = 0.f;

    for (int k0 = 0; k0 < K; k0 += 32) {
        __syncthreads();                       // prev compute done
        gl16(Ab0 + k0, ldsA0);
        gl16(Ab1 + k0, ldsA1);
        gl16(Wb0 + k0, ldsB0);
        gl16(Wb1 + k0, ldsB1);
        __syncthreads();                       // drains vmcnt: tiles ready

        short8 af[4], bf[4];
#pragma unroll
        for (int mi = 0; mi < 4; ++mi)
            af[mi] = *(const short8*)(Asb + (wr*64 + mi*16 + fr)*32 + fq*8);
#pragma unroll
        for (int ni = 0; ni < 4; ++ni)
            bf[ni] = *(const short8*)(Bsb + (wc*64 + ni*16 + fr)*32 + fq*8);
#pragma unroll
        for (int mi = 0; mi < 4; ++mi)
#pragma unroll
            for (int ni = 0; ni < 4; ++ni)
                acc[mi][ni] = __builtin_amdgcn_mfma_f32_16x16x32_bf16(
                    af[mi], bf[ni], acc[mi][ni], 0, 0, 0);
    }

    // bias (per col = wc*64 + ni*16 + fr)
    float bv[4];
#pragma unroll
    for (int ni = 0; ni < 4; ++ni) bv[ni] = bias[col0 + wc*64 + ni*16 + fr];
#pragma unroll
    for (int mi = 0; mi < 4; ++mi)
#pragma unroll
        for (int ni = 0; ni < 4; ++ni)
#pragma unroll
            for (int r = 0; r < 4; ++r) acc[mi][ni][r] += bv[ni];

    __syncthreads();                           // tiles dead; reuse LDS for repack
    float* rp = (float*)lds + w*1088;          // per-wave [16][68] f32
    const int orow = l >> 2, oc = (l & 3) * 16;
#pragma unroll
    for (int mi = 0; mi < 4; ++mi) {
#pragma unroll
        for (int ni = 0; ni < 4; ++ni)
#pragma unroll
            for (int r = 0; r < 4; ++r)
                rp[(fq*4 + r)*68 + ni*16 + fr] = acc[mi][ni][r];
        // wave-lockstep: compiler orders LDS write->read within the wave
        float vrow[16];
#pragma unroll
        for (int j = 0; j < 4; ++j)
            *(f32x4*)&vrow[j*4] = *(const f32x4*)&rp[orow*68 + oc + j*4];
        const size_t grow = (size_t)(row0 + wr*64 + mi*16 + orow);
        const int    gcol = col0 + wc*64 + oc;
        if (OUT_BF16) {
            union { unsigned short s[16]; uint4 u[2]; } pk;
#pragma unroll
            for (int j = 0; j < 16; ++j) pk.s[j] = f2bf(vrow[j]);
            uint4* dst = (uint4*)((unsigned short*)Cout + grow*N + gcol);
            dst[0] = pk.u[0]; dst[1] = pk.u[1];
        } else {
            float* dst = (float*)Cout + grow*N + gcol;
#pragma unroll
            for (int j = 0; j < 4; ++j)
                *(f32x4*)(dst + j*4) = *(const f32x4*)&vrow[j*4];
        }
    }
}

// ---------------------------------------------------------------------------
// V transpose: qkv_b [B*S][3072] (V = cols 2048+h*64+d) -> vt [(b*16+h)*64+d][2048]
// 64x64 tiles through LDS [64][72] (write cols scalar, read rows vector)
// ---------------------------------------------------------------------------
__global__ __launch_bounds__(256) void transpose_v(
    const unsigned short* __restrict__ qkvb, unsigned short* __restrict__ vt)
{
    __shared__ __align__(16) unsigned short T[64*72];
    const int tid = threadIdx.x;
    const int s0 = blockIdx.x * 64, h = blockIdx.y, b = blockIdx.z;
    const unsigned short* src = qkvb + (size_t)b*SEQ*3072 + 2048 + h*64;

    const int r = tid >> 2, c0 = (tid & 3) * 16;
    uint4 u0 = *(const uint4*)(src + (size_t)(s0 + r)*3072 + c0);
    uint4 u1 = *(const uint4*)(src + (size_t)(s0 + r)*3072 + c0 + 8);
    unsigned short e[16];
    *(uint4*)&e[0] = u0; *(uint4*)&e[8] = u1;
#pragma unroll
    for (int i = 0; i < 16; ++i) T[(c0 + i)*72 + r] = e[i];   // transposed write
    __syncthreads();
    const int d = tid >> 2, ss = (tid & 3) * 16;
    uint4 w0 = *(const uint4*)(&T[d*72 + ss]);
    uint4 w1 = *(const uint4*)(&T[d*72 + ss + 8]);
    unsigned short* dst = vt + ((size_t)((b*16 + h)*64 + d))*SEQ + s0 + ss;
    *(uint4*)dst = w0; *(uint4*)(dst + 8) = w1;
}

// ---------------------------------------------------------------------------
// MFMA flash attention. Block = 256 thr (4 waves), QBLK=128 (32 q-rows/wave),
// KVBLK=64. K,Vt staged via global_load_lds; P relayout via padded LDS.
// ---------------------------------------------------------------------------
__global__ __launch_bounds__(256) void attn_mfma(
    const unsigned short* __restrict__ qkvb,
    const unsigned short* __restrict__ vt,
    unsigned short* __restrict__ ctxb)
{
    __shared__ __align__(16) char pool[34816];
    unsigned short* Kt  = (unsigned short*)pool;   // [64][64]
    unsigned short* Vtl = Kt + 4096;               // [64][64] rows=d, cols=kv
    unsigned short* Pl  = Vtl + 4096;              // 4 x [32][72]

    const int tid = threadIdx.x, w = tid >> 6, l = tid & 63;
    const int fr = l & 15, fq = l >> 4;
    const int b = blockIdx.z, h = blockIdx.y;
    const int q0 = blockIdx.x * 128;
    const int wq = q0 + w*32;

    const unsigned short* qb = qkvb + (size_t)b*SEQ*3072 + h*64;
    const unsigned short* kb = qb + 1024;
    const unsigned short* vb = vt + (size_t)((b*16 + h)*64)*SEQ;

    // Q fragments held in registers for the whole KV loop
    short8 qf[2][2];
#pragma unroll
    for (int mf = 0; mf < 2; ++mf)
#pragma unroll
        for (int kk = 0; kk < 2; ++kk)
            qf[mf][kk] = *(const short8*)(qb + (size_t)(wq + mf*16 + fr)*3072
                                          + kk*32 + fq*8);

    f32x4 o[2][4];
    float mrun[2][4], lrun[2][4];
#pragma unroll
    for (int mf = 0; mf < 2; ++mf)
#pragma unroll
        for (int df = 0; df < 4; ++df)
#pragma unroll
            for (int r = 0; r < 4; ++r) o[mf][df][r] = 0.f;
#pragma unroll
    for (int mf = 0; mf < 2; ++mf)
#pragma unroll
        for (int r = 0; r < 4; ++r) { mrun[mf][r] = -1e30f; lrun[mf][r] = 0.f; }

    const int srA = (w*2 + 0)*8 + (l >> 3);
    const int srB = (w*2 + 1)*8 + (l >> 3);
    const int sc  = (l & 7) * 8;
    unsigned short* Pw = Pl + w*(32*72);

    for (int kv0 = 0; kv0 < SEQ; kv0 += 64) {
        __syncthreads();
        gl16(kb + (size_t)(kv0 + srA)*3072 + sc, Kt  + (w*2 + 0)*512);
        gl16(kb + (size_t)(kv0 + srB)*3072 + sc, Kt  + (w*2 + 1)*512);
        gl16(vb + (size_t)srA*SEQ + kv0 + sc,    Vtl + (w*2 + 0)*512);
        gl16(vb + (size_t)srB*SEQ + kv0 + sc,    Vtl + (w*2 + 1)*512);
        __syncthreads();

        // ---- S = Q K^T ----
        f32x4 s[2][4];
#pragma unroll
        for (int mf = 0; mf < 2; ++mf)
#pragma unroll
            for (int nf = 0; nf < 4; ++nf)
#pragma unroll
                for (int r = 0; r < 4; ++r) s[mf][nf][r] = 0.f;
#pragma unroll
        for (int nf = 0; nf < 4; ++nf) {
            const short8 k0f = *(const short8*)(Kt + (nf*16 + fr)*64 + fq*8);
            const short8 k1f = *(const short8*)(Kt + (nf*16 + fr)*64 + 32 + fq*8);
#pragma unroll
            for (int mf = 0; mf < 2; ++mf) {
                s[mf][nf] = __builtin_amdgcn_mfma_f32_16x16x32_bf16(qf[mf][0], k0f, s[mf][nf], 0,0,0);
                s[mf][nf] = __builtin_amdgcn_mfma_f32_16x16x32_bf16(qf[mf][1], k1f, s[mf][nf], 0,0,0);
            }
        }

        // ---- online softmax (rows = mf*16 + fq*4 + r, reduce across 16 lanes) ----
#pragma unroll
        for (int mf = 0; mf < 2; ++mf) {
            float corr[4];
#pragma unroll
            for (int r = 0; r < 4; ++r) {
                float mx = fmaxf(fmaxf(s[mf][0][r], s[mf][1][r]),
                                 fmaxf(s[mf][2][r], s[mf][3][r])) * SCALE;
#pragma unroll
                for (int dd = 1; dd < 16; dd <<= 1)
                    mx = fmaxf(mx, __shfl_xor(mx, dd, 16));
                const float mnew = fmaxf(mrun[mf][r], mx);
                corr[r] = __expf(mrun[mf][r] - mnew);
                mrun[mf][r] = mnew;
            }
            float psum[4] = {0.f, 0.f, 0.f, 0.f};
#pragma unroll
            for (int nf = 0; nf < 4; ++nf)
#pragma unroll
                for (int r = 0; r < 4; ++r) {
                    const float p = __expf(s[mf][nf][r]*SCALE - mrun[mf][r]);
                    psum[r] += p;
                    Pw[(mf*16 + fq*4 + r)*72 + nf*16 + fr] = f2bf(p);
                }
#pragma unroll
            for (int r = 0; r < 4; ++r) {
#pragma unroll
                for (int dd = 1; dd < 16; dd <<= 1)
                    psum[r] += __shfl_xor(psum[r], dd, 16);
                lrun[mf][r] = lrun[mf][r]*corr[r] + psum[r];
            }
#pragma unroll
            for (int df = 0; df < 4; ++df)
#pragma unroll
                for (int r = 0; r < 4; ++r) o[mf][df][r] *= corr[r];
        }

        // ---- O += P V ----
        short8 pa[2][2];
#pragma unroll
        for (int mf = 0; mf < 2; ++mf)
#pragma unroll
            for (int kk = 0; kk < 2; ++kk)
                pa[mf][kk] = *(const short8*)(Pw + (mf*16 + fr)*72 + kk*32 + fq*8);
#pragma unroll
        for (int df = 0; df < 4; ++df) {
            const short8 v0f = *(const short8*)(Vtl + (df*16 + fr)*64 + fq*8);
            const short8 v1f = *(const short8*)(Vtl + (df*16 + fr)*64 + 32 + fq*8);
#pragma unroll
            for (int mf = 0; mf < 2; ++mf) {
                o[mf][df] = __builtin_amdgcn_mfma_f32_16x16x32_bf16(pa[mf][0], v0f, o[mf][df], 0,0,0);
                o[mf][df] = __builtin_amdgcn_mfma_f32_16x16x32_bf16(pa[mf][1], v1f, o[mf][df], 0,0,0);
            }
        }
    }

    // ---- normalize + coalesced store via per-wave LDS repack ----
    __syncthreads();
    float* rp = (float*)(pool + w*8704);   // [32][68] f32
#pragma unroll
    for (int mf = 0; mf < 2; ++mf)
#pragma unroll
        for (int df = 0; df < 4; ++df)
#pragma unroll
            for (int r = 0; r < 4; ++r)
                rp[(mf*16 + fq*4 + r)*68 + df*16 + fr] = o[mf][df][r] / lrun[mf][r];
    const int orow = l >> 1, oc = (l & 1)*32;
    float vr[32];
#pragma unroll
    for (int j = 0; j < 8; ++j)
        *(f32x4*)&vr[j*4] = *(const f32x4*)&rp[orow*68 + oc + j*4];
    union { unsigned short s[32]; uint4 u[4]; } pk;
#pragma unroll
    for (int j = 0; j < 32; ++j) pk.s[j] = f2bf(vr[j]);
    unsigned short* dst = ctxb + (size_t)(b*SEQ + q0 + w*32 + orow)*DIMC + h*64 + oc;
#pragma unroll
    for (int j = 0; j < 4; ++j) *((uint4*)dst + j) = pk.u[j];
}

} // namespace

extern "C" void kernel_launch(void* const* d_in, const int* in_sizes, int n_in,
                              void* d_out, int out_size, void* d_ws, size_t ws_size,
                              hipStream_t stream)
{
    const float* x     = (const float*)d_in[0];
    const float* qkv_w = (const float*)d_in[1];
    const float* qkv_b = (const float*)d_in[2];
    const float* out_w = (const float*)d_in[3];
    const float* out_b = (const float*)d_in[4];

    // workspace carve (bf16 buffers), ~109 MB total
    unsigned short* xb   = (unsigned short*)d_ws;              // [8192][1024]
    unsigned short* wqb  = xb   + (size_t)8192*1024;           // [3072][1024]
    unsigned short* wob  = wqb  + (size_t)3072*1024;           // [1024][1024]
    unsigned short* qkvb = wob  + (size_t)1024*1024;           // [8192][3072]
    unsigned short* vtw  = qkvb + (size_t)8192*3072;           // [4096][2048]
    unsigned short* ctxb = vtw  + (size_t)4096*2048;           // [8192][1024]

    // 1) fp32 -> bf16 conversions
    cvt_f32_bf16<<<2048, 256, 0, stream>>>(x,     xb,  8192*1024/8);
    cvt_f32_bf16<<<1024, 256, 0, stream>>>(qkv_w, wqb, 3072*1024/8);
    cvt_f32_bf16<<<512,  256, 0, stream>>>(out_w, wob, 1024*1024/8);

    // 2) QKV projection (bf16 out): [8192,1024]x[3072,1024]^T
    gemm_bf16_mfma<1><<<dim3(24, 64), 256, 0, stream>>>(
        xb, wqb, qkv_b, (void*)qkvb, 8192, 3072, 1024);

    // 3) V transpose for PV's B-operand
    transpose_v<<<dim3(SEQ/64, HEADS, BATCH), 256, 0, stream>>>(qkvb, vtw);

    // 4) flash attention (bf16 MFMA) -> ctx bf16
    attn_mfma<<<dim3(SEQ/128, HEADS, BATCH), 256, 0, stream>>>(qkvb, vtw, ctxb);

    // 5) output projection (f32 out): [8192,1024]x[1024,1024]^T + bias
    gemm_bf16_mfma<0><<<dim3(8, 64), 256, 0, stream>>>(
        ctxb, wob, out_b, d_out, 8192, 1024, 1024);
}

// Round 5
// 349.765 us; speedup vs baseline: 6.2284x; 1.0891x over previous
//
#include <hip/hip_runtime.h>

namespace {

constexpr int DIMC  = 1024;
constexpr int HEADS = 16;
constexpr int HD    = 64;
constexpr int BATCH = 4;
constexpr int SEQ   = 2048;
constexpr float SC2 = 0.18033688011112042f;   // (1/sqrt(64)) * log2(e)

typedef __attribute__((ext_vector_type(8))) short short8;   // 8 bf16 (4 VGPRs)
typedef __attribute__((ext_vector_type(4))) float f32x4;

__device__ __forceinline__ unsigned short f2bf(float f) {
    union { float f; unsigned u; } v; v.f = f;
    unsigned r = v.u + 0x7fffu + ((v.u >> 16) & 1u);   // RNE
    return (unsigned short)(r >> 16);
}

// async global->LDS, 16B per lane; ldst must be wave-uniform base (HW adds lane*16)
__device__ __forceinline__ void gl16(const unsigned short* gsrc, const unsigned short* ldst) {
    __builtin_amdgcn_global_load_lds(
        (const __attribute__((address_space(1))) void*)gsrc,
        (__attribute__((address_space(3))) void*)ldst, 16, 0, 0);
}

// ---------------------------------------------------------------------------
// fp32 -> bf16 elementwise (8 elems/thread/iter)
// ---------------------------------------------------------------------------
__global__ __launch_bounds__(256) void cvt_f32_bf16(
    const float* __restrict__ in, unsigned short* __restrict__ out, int n8)
{
    for (int i = blockIdx.x * blockDim.x + threadIdx.x; i < n8;
         i += gridDim.x * blockDim.x) {
        const float4 a = ((const float4*)in)[2*i];
        const float4 b = ((const float4*)in)[2*i + 1];
        union { unsigned short s[8]; uint4 u; } p;
        p.s[0]=f2bf(a.x); p.s[1]=f2bf(a.y); p.s[2]=f2bf(a.z); p.s[3]=f2bf(a.w);
        p.s[4]=f2bf(b.x); p.s[5]=f2bf(b.y); p.s[6]=f2bf(b.z); p.s[7]=f2bf(b.w);
        ((uint4*)out)[i] = p.u;
    }
}

// ---------------------------------------------------------------------------
// bf16 GEMM: C[M,N] = A[M,K] @ W[N,K]^T + bias.  128x128 tile, BK=32,
// 4 waves (2x2), 64x64/wave. Double-buffered global_load_lds prefetch
// (1 barrier / K-step); XOR-swizzled LDS (chunk ^ (row>>1)&3, 16B chunks,
// 64B rows) applied via pre-swizzled global source + swizzled ds_read.
// ---------------------------------------------------------------------------
template<int OUT_BF16>
__global__ __launch_bounds__(256) void gemm_bf16_mfma(
    const unsigned short* __restrict__ A, const unsigned short* __restrict__ W,
    const float* __restrict__ bias, void* __restrict__ Cout,
    int M, int N, int K)
{
    __shared__ __align__(16) char lds[32768];   // A0 B0 A1 B1 (8KB each)
    unsigned short* base = (unsigned short*)lds;

    const int tid = threadIdx.x;
    const int w = tid >> 6, l = tid & 63;
    const int wr = w >> 1, wc = w & 1;
    const int fr = l & 15, fq = l >> 4;
    const int row0 = blockIdx.y * 128, col0 = blockIdx.x * 128;

    // staging: per gl16 chunk = 16 rows x 32 cols; lane l -> row l>>2, chunk l&3
    const int sr0 = (w*2 + 0)*16 + (l >> 2);
    const int sr1 = (w*2 + 1)*16 + (l >> 2);
    const int skz = (((l & 3) ^ ((l >> 3) & 3))) * 8;   // swizzled source col

    const unsigned short* Ab0 = A + (size_t)(row0 + sr0)*K + skz;
    const unsigned short* Ab1 = A + (size_t)(row0 + sr1)*K + skz;
    const unsigned short* Wb0 = W + (size_t)(col0 + sr0)*K + skz;
    const unsigned short* Wb1 = W + (size_t)(col0 + sr1)*K + skz;

    f32x4 acc[4][4];
#pragma unroll
    for (int mi = 0; mi < 4; ++mi)
#pragma unroll
        for (int ni = 0; ni < 4; ++ni)
#pragma unroll
            for (int r = 0; r < 4; ++r) acc[mi][ni][r] = 0.f;

    // frag read col chunk (swizzled): c' = fq ^ ((fr>>1)&3)
    const int cfa = (fq ^ ((fr >> 1) & 3)) * 8;

    auto stage = [&](int k0, int buf) {
        unsigned short* Ad = base + buf*8192;
        unsigned short* Wd = Ad + 4096;
        gl16(Ab0 + k0, Ad + (w*2 + 0)*512);
        gl16(Ab1 + k0, Ad + (w*2 + 1)*512);
        gl16(Wb0 + k0, Wd + (w*2 + 0)*512);
        gl16(Wb1 + k0, Wd + (w*2 + 1)*512);
    };

    stage(0, 0);
    for (int k0 = 0; k0 < K; k0 += 32) {
        const int buf = (k0 >> 5) & 1;
        __syncthreads();                    // drains vmcnt: tile(k0) ready; buf^1 free
        if (k0 + 32 < K) stage(k0 + 32, buf ^ 1);

        const unsigned short* Ac = base + buf*8192;
        const unsigned short* Wc = Ac + 4096;
        short8 af[4], bf[4];
#pragma unroll
        for (int mi = 0; mi < 4; ++mi)
            af[mi] = *(const short8*)(Ac + (wr*64 + mi*16 + fr)*32 + cfa);
#pragma unroll
        for (int ni = 0; ni < 4; ++ni)
            bf[ni] = *(const short8*)(Wc + (wc*64 + ni*16 + fr)*32 + cfa);
#pragma unroll
        for (int mi = 0; mi < 4; ++mi)
#pragma unroll
            for (int ni = 0; ni < 4; ++ni)
                acc[mi][ni] = __builtin_amdgcn_mfma_f32_16x16x32_bf16(
                    af[mi], bf[ni], acc[mi][ni], 0, 0, 0);
    }

    // bias (per col = wc*64 + ni*16 + fr)
    float bv[4];
#pragma unroll
    for (int ni = 0; ni < 4; ++ni) bv[ni] = bias[col0 + wc*64 + ni*16 + fr];
#pragma unroll
    for (int mi = 0; mi < 4; ++mi)
#pragma unroll
        for (int ni = 0; ni < 4; ++ni)
#pragma unroll
            for (int r = 0; r < 4; ++r) acc[mi][ni][r] += bv[ni];

    __syncthreads();                           // tiles dead; reuse LDS for repack
    float* rp = (float*)lds + w*1088;          // per-wave [16][68] f32
    const int orow = l >> 2, oc = (l & 3) * 16;
#pragma unroll
    for (int mi = 0; mi < 4; ++mi) {
#pragma unroll
        for (int ni = 0; ni < 4; ++ni)
#pragma unroll
            for (int r = 0; r < 4; ++r)
                rp[(fq*4 + r)*68 + ni*16 + fr] = acc[mi][ni][r];
        // wave-lockstep: compiler orders LDS write->read within the wave
        float vrow[16];
#pragma unroll
        for (int j = 0; j < 4; ++j)
            *(f32x4*)&vrow[j*4] = *(const f32x4*)&rp[orow*68 + oc + j*4];
        const size_t grow = (size_t)(row0 + wr*64 + mi*16 + orow);
        const int    gcol = col0 + wc*64 + oc;
        if (OUT_BF16) {
            union { unsigned short s[16]; uint4 u[2]; } pk;
#pragma unroll
            for (int j = 0; j < 16; ++j) pk.s[j] = f2bf(vrow[j]);
            uint4* dst = (uint4*)((unsigned short*)Cout + grow*N + gcol);
            dst[0] = pk.u[0]; dst[1] = pk.u[1];
        } else {
            float* dst = (float*)Cout + grow*N + gcol;
#pragma unroll
            for (int j = 0; j < 4; ++j)
                *(f32x4*)(dst + j*4) = *(const f32x4*)&vrow[j*4];
        }
    }
}

// ---------------------------------------------------------------------------
// V transpose: qkv_b [B*S][3072] (V = cols 2048+h*64+d) -> vt [(b*16+h)*64+d][2048]
// ---------------------------------------------------------------------------
__global__ __launch_bounds__(256) void transpose_v(
    const unsigned short* __restrict__ qkvb, unsigned short* __restrict__ vt)
{
    __shared__ __align__(16) unsigned short T[64*72];
    const int tid = threadIdx.x;
    const int s0 = blockIdx.x * 64, h = blockIdx.y, b = blockIdx.z;
    const unsigned short* src = qkvb + (size_t)b*SEQ*3072 + 2048 + h*64;

    const int r = tid >> 2, c0 = (tid & 3) * 16;
    uint4 u0 = *(const uint4*)(src + (size_t)(s0 + r)*3072 + c0);
    uint4 u1 = *(const uint4*)(src + (size_t)(s0 + r)*3072 + c0 + 8);
    unsigned short e[16];
    *(uint4*)&e[0] = u0; *(uint4*)&e[8] = u1;
#pragma unroll
    for (int i = 0; i < 16; ++i) T[(c0 + i)*72 + r] = e[i];   // transposed write
    __syncthreads();
    const int d = tid >> 2, ss = (tid & 3) * 16;
    uint4 w0 = *(const uint4*)(&T[d*72 + ss]);
    uint4 w1 = *(const uint4*)(&T[d*72 + ss + 8]);
    unsigned short* dst = vt + ((size_t)((b*16 + h)*64 + d))*SEQ + s0 + ss;
    *(uint4*)dst = w0; *(uint4*)(dst + 8) = w1;
}

// ---------------------------------------------------------------------------
// MFMA flash attention. 4 waves, QBLK=128 (32 q-rows/wave), KVBLK=64.
// Double-buffered K/Vt prefetch (1 barrier/tile); XOR-swizzled K/Vt
// (chunk ^ row&7, 16B chunks, 128B rows) via pre-swizzled global source.
// Softmax in exp2 domain; P packed to bf16 with v_cvt_pk_bf16_f32.
// ---------------------------------------------------------------------------
__global__ __launch_bounds__(256) void attn_mfma(
    const unsigned short* __restrict__ qkvb,
    const unsigned short* __restrict__ vt,
    unsigned short* __restrict__ ctxb)
{
    __shared__ __align__(16) char pool[51200];
    unsigned short* Kb0 = (unsigned short*)pool;   // K0 K1 V0 V1: [64][64] each
    unsigned short* Vb0 = Kb0 + 8192;
    unsigned short* Pl  = Kb0 + 16384;             // 4 x [32][72]

    const int tid = threadIdx.x, w = tid >> 6, l = tid & 63;
    const int fr = l & 15, fq = l >> 4;
    const int b = blockIdx.z, h = blockIdx.y;
    const int q0 = blockIdx.x * 128;
    const int wq = q0 + w*32;

    const unsigned short* qb = qkvb + (size_t)b*SEQ*3072 + h*64;
    const unsigned short* kb = qb + 1024;
    const unsigned short* vb = vt + (size_t)((b*16 + h)*64)*SEQ;

    // Q fragments in registers for the whole KV loop
    short8 qf[2][2];
#pragma unroll
    for (int mf = 0; mf < 2; ++mf)
#pragma unroll
        for (int kk = 0; kk < 2; ++kk)
            qf[mf][kk] = *(const short8*)(qb + (size_t)(wq + mf*16 + fr)*3072
                                          + kk*32 + fq*8);

    f32x4 o[2][4];
    float mrun[2][4], lrun[2][4];
#pragma unroll
    for (int mf = 0; mf < 2; ++mf)
#pragma unroll
        for (int df = 0; df < 4; ++df)
#pragma unroll
            for (int r = 0; r < 4; ++r) o[mf][df][r] = 0.f;
#pragma unroll
    for (int mf = 0; mf < 2; ++mf)
#pragma unroll
        for (int r = 0; r < 4; ++r) { mrun[mf][r] = -1e30f; lrun[mf][r] = 0.f; }

    // staging: per gl16 chunk = 8 rows x 64 cols; lane l -> row l>>3, chunk l&7
    const int srA = (w*2 + 0)*8 + (l >> 3);
    const int srB = (w*2 + 1)*8 + (l >> 3);
    const int scz = ((l & 7) ^ (l >> 3)) * 8;          // swizzled source col
    unsigned short* Pw = Pl + w*2304;

    // frag read swizzle: chunk c0 = fq ^ (fr&7); second half chunk = c0^4
    const int c0e = (fq ^ (fr & 7)) * 8;
    const int c1e = c0e ^ 32;

    auto stage = [&](int kv0, int buf) {
        unsigned short* Kd = Kb0 + buf*4096;
        unsigned short* Vd = Vb0 + buf*4096;
        gl16(kb + (size_t)(kv0 + srA)*3072 + scz, Kd + (w*2 + 0)*512);
        gl16(kb + (size_t)(kv0 + srB)*3072 + scz, Kd + (w*2 + 1)*512);
        gl16(vb + (size_t)srA*SEQ + kv0 + scz,    Vd + (w*2 + 0)*512);
        gl16(vb + (size_t)srB*SEQ + kv0 + scz,    Vd + (w*2 + 1)*512);
    };

    stage(0, 0);
    for (int kv0 = 0; kv0 < SEQ; kv0 += 64) {
        const int buf = (kv0 >> 6) & 1;
        __syncthreads();                 // tile(kv0) DMA done; buf^1 free
        if (kv0 + 64 < SEQ) stage(kv0 + 64, buf ^ 1);

        const unsigned short* Kc = Kb0 + buf*4096;
        const unsigned short* Vc = Vb0 + buf*4096;

        // ---- S = Q K^T ----
        f32x4 s[2][4];
#pragma unroll
        for (int mf = 0; mf < 2; ++mf)
#pragma unroll
            for (int nf = 0; nf < 4; ++nf)
#pragma unroll
                for (int r = 0; r < 4; ++r) s[mf][nf][r] = 0.f;
#pragma unroll
        for (int nf = 0; nf < 4; ++nf) {
            const short8 k0f = *(const short8*)(Kc + (nf*16 + fr)*64 + c0e);
            const short8 k1f = *(const short8*)(Kc + (nf*16 + fr)*64 + c1e);
#pragma unroll
            for (int mf = 0; mf < 2; ++mf) {
                s[mf][nf] = __builtin_amdgcn_mfma_f32_16x16x32_bf16(qf[mf][0], k0f, s[mf][nf], 0,0,0);
                s[mf][nf] = __builtin_amdgcn_mfma_f32_16x16x32_bf16(qf[mf][1], k1f, s[mf][nf], 0,0,0);
            }
        }

        // ---- online softmax, exp2 domain (rows = mf*16+fq*4+r, 16-lane reduce) ----
#pragma unroll
        for (int mf = 0; mf < 2; ++mf) {
            float t[4][4];
#pragma unroll
            for (int nf = 0; nf < 4; ++nf)
#pragma unroll
                for (int r = 0; r < 4; ++r) t[nf][r] = s[mf][nf][r] * SC2;
            float corr[4];
#pragma unroll
            for (int r = 0; r < 4; ++r) {
                float mx = fmaxf(fmaxf(t[0][r], t[1][r]), fmaxf(t[2][r], t[3][r]));
#pragma unroll
                for (int dd = 1; dd < 16; dd <<= 1)
                    mx = fmaxf(mx, __shfl_xor(mx, dd, 16));
                const float mnew = fmaxf(mrun[mf][r], mx);
                corr[r] = exp2f(mrun[mf][r] - mnew);
                mrun[mf][r] = mnew;
            }
            float psum[4] = {0.f, 0.f, 0.f, 0.f};
#pragma unroll
            for (int nf = 0; nf < 4; ++nf)
#pragma unroll
                for (int rr = 0; rr < 4; rr += 2) {
                    const float p0 = exp2f(t[nf][rr]   - mrun[mf][rr]);
                    const float p1 = exp2f(t[nf][rr+1] - mrun[mf][rr+1]);
                    psum[rr]   += p0;
                    psum[rr+1] += p1;
                    unsigned u;
                    asm("v_cvt_pk_bf16_f32 %0, %1, %2" : "=v"(u) : "v"(p0), "v"(p1));
                    Pw[(mf*16 + fq*4 + rr  )*72 + nf*16 + fr] = (unsigned short)u;
                    Pw[(mf*16 + fq*4 + rr+1)*72 + nf*16 + fr] = (unsigned short)(u >> 16);
                }
#pragma unroll
            for (int r = 0; r < 4; ++r) {
#pragma unroll
                for (int dd = 1; dd < 16; dd <<= 1)
                    psum[r] += __shfl_xor(psum[r], dd, 16);
                lrun[mf][r] = lrun[mf][r]*corr[r] + psum[r];
            }
#pragma unroll
            for (int df = 0; df < 4; ++df)
#pragma unroll
                for (int r = 0; r < 4; ++r) o[mf][df][r] *= corr[r];
        }

        // ---- O += P V  (P is wave-local: no barrier needed) ----
        short8 pa[2][2];
#pragma unroll
        for (int mf = 0; mf < 2; ++mf)
#pragma unroll
            for (int kk = 0; kk < 2; ++kk)
                pa[mf][kk] = *(const short8*)(Pw + (mf*16 + fr)*72 + kk*32 + fq*8);
#pragma unroll
        for (int df = 0; df < 4; ++df) {
            const short8 v0f = *(const short8*)(Vc + (df*16 + fr)*64 + c0e);
            const short8 v1f = *(const short8*)(Vc + (df*16 + fr)*64 + c1e);
#pragma unroll
            for (int mf = 0; mf < 2; ++mf) {
                o[mf][df] = __builtin_amdgcn_mfma_f32_16x16x32_bf16(pa[mf][0], v0f, o[mf][df], 0,0,0);
                o[mf][df] = __builtin_amdgcn_mfma_f32_16x16x32_bf16(pa[mf][1], v1f, o[mf][df], 0,0,0);
            }
        }
    }

    // ---- normalize + coalesced store via per-wave LDS repack ----
    __syncthreads();
    float* rp = (float*)(pool + w*8704);   // [32][68] f32
#pragma unroll
    for (int mf = 0; mf < 2; ++mf)
#pragma unroll
        for (int df = 0; df < 4; ++df)
#pragma unroll
            for (int r = 0; r < 4; ++r)
                rp[(mf*16 + fq*4 + r)*68 + df*16 + fr] = o[mf][df][r] / lrun[mf][r];
    const int orow = l >> 1, oc = (l & 1)*32;
    float vr[32];
#pragma unroll
    for (int j = 0; j < 8; ++j)
        *(f32x4*)&vr[j*4] = *(const f32x4*)&rp[orow*68 + oc + j*4];
    union { unsigned short s[32]; uint4 u[4]; } pk;
#pragma unroll
    for (int j = 0; j < 32; ++j) pk.s[j] = f2bf(vr[j]);
    unsigned short* dst = ctxb + (size_t)(b*SEQ + q0 + w*32 + orow)*DIMC + h*64 + oc;
#pragma unroll
    for (int j = 0; j < 4; ++j) *((uint4*)dst + j) = pk.u[j];
}

} // namespace

extern "C" void kernel_launch(void* const* d_in, const int* in_sizes, int n_in,
                              void* d_out, int out_size, void* d_ws, size_t ws_size,
                              hipStream_t stream)
{
    const float* x     = (const float*)d_in[0];
    const float* qkv_w = (const float*)d_in[1];
    const float* qkv_b = (const float*)d_in[2];
    const float* out_w = (const float*)d_in[3];
    const float* out_b = (const float*)d_in[4];

    // workspace carve (bf16 buffers), ~109 MB total
    unsigned short* xb   = (unsigned short*)d_ws;              // [8192][1024]
    unsigned short* wqb  = xb   + (size_t)8192*1024;           // [3072][1024]
    unsigned short* wob  = wqb  + (size_t)3072*1024;           // [1024][1024]
    unsigned short* qkvb = wob  + (size_t)1024*1024;           // [8192][3072]
    unsigned short* vtw  = qkvb + (size_t)8192*3072;           // [4096][2048]
    unsigned short* ctxb = vtw  + (size_t)4096*2048;           // [8192][1024]

    // 1) fp32 -> bf16 conversions
    cvt_f32_bf16<<<2048, 256, 0, stream>>>(x,     xb,  8192*1024/8);
    cvt_f32_bf16<<<1024, 256, 0, stream>>>(qkv_w, wqb, 3072*1024/8);
    cvt_f32_bf16<<<512,  256, 0, stream>>>(out_w, wob, 1024*1024/8);

    // 2) QKV projection (bf16 out): [8192,1024]x[3072,1024]^T
    gemm_bf16_mfma<1><<<dim3(24, 64), 256, 0, stream>>>(
        xb, wqb, qkv_b, (void*)qkvb, 8192, 3072, 1024);

    // 3) V transpose for PV's B-operand
    transpose_v<<<dim3(SEQ/64, HEADS, BATCH), 256, 0, stream>>>(qkvb, vtw);

    // 4) flash attention (bf16 MFMA) -> ctx bf16
    attn_mfma<<<dim3(SEQ/128, HEADS, BATCH), 256, 0, stream>>>(qkvb, vtw, ctxb);

    // 5) output projection (f32 out): [8192,1024]x[1024,1024]^T + bias
    gemm_bf16_mfma<0><<<dim3(8, 64), 256, 0, stream>>>(
        ctxb, wob, out_b, d_out, 8192, 1024, 1024);
}

// Round 6
// 264.302 us; speedup vs baseline: 8.2424x; 1.3234x over previous
//
#include <hip/hip_runtime.h>

namespace {

constexpr int DIMC  = 1024;
constexpr int HEADS = 16;
constexpr int HD    = 64;
constexpr int BATCH = 4;
constexpr int SEQ   = 2048;
constexpr float SC2 = 0.18033688011112042f;   // (1/sqrt(64)) * log2(e)
constexpr float THR_RAW = 44.3614f;           // defer-max threshold: P <= 2^8

typedef __attribute__((ext_vector_type(8))) short short8;   // 8 bf16 (4 VGPRs)
typedef __attribute__((ext_vector_type(4))) float f32x4;

__device__ __forceinline__ unsigned short f2bf(float f) {
    union { float f; unsigned u; } v; v.f = f;
    unsigned r = v.u + 0x7fffu + ((v.u >> 16) & 1u);   // RNE
    return (unsigned short)(r >> 16);
}

// async global->LDS, 16B per lane; ldst must be wave-uniform base (HW adds lane*16)
__device__ __forceinline__ void gl16(const unsigned short* gsrc, const unsigned short* ldst) {
    __builtin_amdgcn_global_load_lds(
        (const __attribute__((address_space(1))) void*)gsrc,
        (__attribute__((address_space(3))) void*)ldst, 16, 0, 0);
}

// ---------------------------------------------------------------------------
// fp32 -> bf16 elementwise (8 elems/thread/iter)
// ---------------------------------------------------------------------------
__global__ __launch_bounds__(256) void cvt_f32_bf16(
    const float* __restrict__ in, unsigned short* __restrict__ out, int n8)
{
    for (int i = blockIdx.x * blockDim.x + threadIdx.x; i < n8;
         i += gridDim.x * blockDim.x) {
        const float4 a = ((const float4*)in)[2*i];
        const float4 b = ((const float4*)in)[2*i + 1];
        union { unsigned short s[8]; uint4 u; } p;
        p.s[0]=f2bf(a.x); p.s[1]=f2bf(a.y); p.s[2]=f2bf(a.z); p.s[3]=f2bf(a.w);
        p.s[4]=f2bf(b.x); p.s[5]=f2bf(b.y); p.s[6]=f2bf(b.z); p.s[7]=f2bf(b.w);
        ((uint4*)out)[i] = p.u;
    }
}

// ---------------------------------------------------------------------------
// bf16 GEMM: C[M,N] = A[M,K] @ W[N,K]^T + bias.  128x128 tile, BK=32,
// 4 waves (2x2), 64x64/wave. Double-buffered global_load_lds prefetch;
// XOR-swizzled LDS via pre-swizzled global source + swizzled ds_read.
// ---------------------------------------------------------------------------
template<int OUT_BF16>
__global__ __launch_bounds__(256) void gemm_bf16_mfma(
    const unsigned short* __restrict__ A, const unsigned short* __restrict__ W,
    const float* __restrict__ bias, void* __restrict__ Cout,
    int M, int N, int K)
{
    __shared__ __align__(16) char lds[32768];   // A0 B0 A1 B1 (8KB each)
    unsigned short* base = (unsigned short*)lds;

    const int tid = threadIdx.x;
    const int w = tid >> 6, l = tid & 63;
    const int wr = w >> 1, wc = w & 1;
    const int fr = l & 15, fq = l >> 4;
    const int row0 = blockIdx.y * 128, col0 = blockIdx.x * 128;

    const int sr0 = (w*2 + 0)*16 + (l >> 2);
    const int sr1 = (w*2 + 1)*16 + (l >> 2);
    const int skz = (((l & 3) ^ ((l >> 3) & 3))) * 8;   // swizzled source col

    const unsigned short* Ab0 = A + (size_t)(row0 + sr0)*K + skz;
    const unsigned short* Ab1 = A + (size_t)(row0 + sr1)*K + skz;
    const unsigned short* Wb0 = W + (size_t)(col0 + sr0)*K + skz;
    const unsigned short* Wb1 = W + (size_t)(col0 + sr1)*K + skz;

    f32x4 acc[4][4];
#pragma unroll
    for (int mi = 0; mi < 4; ++mi)
#pragma unroll
        for (int ni = 0; ni < 4; ++ni)
#pragma unroll
            for (int r = 0; r < 4; ++r) acc[mi][ni][r] = 0.f;

    const int cfa = (fq ^ ((fr >> 1) & 3)) * 8;

    auto stage = [&](int k0, int buf) {
        unsigned short* Ad = base + buf*8192;
        unsigned short* Wd = Ad + 4096;
        gl16(Ab0 + k0, Ad + (w*2 + 0)*512);
        gl16(Ab1 + k0, Ad + (w*2 + 1)*512);
        gl16(Wb0 + k0, Wd + (w*2 + 0)*512);
        gl16(Wb1 + k0, Wd + (w*2 + 1)*512);
    };

    stage(0, 0);
    for (int k0 = 0; k0 < K; k0 += 32) {
        const int buf = (k0 >> 5) & 1;
        __syncthreads();                    // drains vmcnt: tile(k0) ready
        if (k0 + 32 < K) stage(k0 + 32, buf ^ 1);

        const unsigned short* Ac = base + buf*8192;
        const unsigned short* Wc = Ac + 4096;
        short8 af[4], bf[4];
#pragma unroll
        for (int mi = 0; mi < 4; ++mi)
            af[mi] = *(const short8*)(Ac + (wr*64 + mi*16 + fr)*32 + cfa);
#pragma unroll
        for (int ni = 0; ni < 4; ++ni)
            bf[ni] = *(const short8*)(Wc + (wc*64 + ni*16 + fr)*32 + cfa);
#pragma unroll
        for (int mi = 0; mi < 4; ++mi)
#pragma unroll
            for (int ni = 0; ni < 4; ++ni)
                acc[mi][ni] = __builtin_amdgcn_mfma_f32_16x16x32_bf16(
                    af[mi], bf[ni], acc[mi][ni], 0, 0, 0);
    }

    float bv[4];
#pragma unroll
    for (int ni = 0; ni < 4; ++ni) bv[ni] = bias[col0 + wc*64 + ni*16 + fr];
#pragma unroll
    for (int mi = 0; mi < 4; ++mi)
#pragma unroll
        for (int ni = 0; ni < 4; ++ni)
#pragma unroll
            for (int r = 0; r < 4; ++r) acc[mi][ni][r] += bv[ni];

    __syncthreads();                           // tiles dead; reuse LDS for repack
    float* rp = (float*)lds + w*1088;          // per-wave [16][68] f32
    const int orow = l >> 2, oc = (l & 3) * 16;
#pragma unroll
    for (int mi = 0; mi < 4; ++mi) {
#pragma unroll
        for (int ni = 0; ni < 4; ++ni)
#pragma unroll
            for (int r = 0; r < 4; ++r)
                rp[(fq*4 + r)*68 + ni*16 + fr] = acc[mi][ni][r];
        float vrow[16];
#pragma unroll
        for (int j = 0; j < 4; ++j)
            *(f32x4*)&vrow[j*4] = *(const f32x4*)&rp[orow*68 + oc + j*4];
        const size_t grow = (size_t)(row0 + wr*64 + mi*16 + orow);
        const int    gcol = col0 + wc*64 + oc;
        if (OUT_BF16) {
            union { unsigned short s[16]; uint4 u[2]; } pk;
#pragma unroll
            for (int j = 0; j < 16; ++j) pk.s[j] = f2bf(vrow[j]);
            uint4* dst = (uint4*)((unsigned short*)Cout + grow*N + gcol);
            dst[0] = pk.u[0]; dst[1] = pk.u[1];
        } else {
            float* dst = (float*)Cout + grow*N + gcol;
#pragma unroll
            for (int j = 0; j < 4; ++j)
                *(f32x4*)(dst + j*4) = *(const f32x4*)&vrow[j*4];
        }
    }
}

// ---------------------------------------------------------------------------
// V transpose: qkv_b [B*S][3072] (V = cols 2048+h*64+d) -> vt [(b*16+h)*64+d][2048]
// ---------------------------------------------------------------------------
__global__ __launch_bounds__(256) void transpose_v(
    const unsigned short* __restrict__ qkvb, unsigned short* __restrict__ vt)
{
    __shared__ __align__(16) unsigned short T[64*72];
    const int tid = threadIdx.x;
    const int s0 = blockIdx.x * 64, h = blockIdx.y, b = blockIdx.z;
    const unsigned short* src = qkvb + (size_t)b*SEQ*3072 + 2048 + h*64;

    const int r = tid >> 2, c0 = (tid & 3) * 16;
    uint4 u0 = *(const uint4*)(src + (size_t)(s0 + r)*3072 + c0);
    uint4 u1 = *(const uint4*)(src + (size_t)(s0 + r)*3072 + c0 + 8);
    unsigned short e[16];
    *(uint4*)&e[0] = u0; *(uint4*)&e[8] = u1;
#pragma unroll
    for (int i = 0; i < 16; ++i) T[(c0 + i)*72 + r] = e[i];
    __syncthreads();
    const int d = tid >> 2, ss = (tid & 3) * 16;
    uint4 w0 = *(const uint4*)(&T[d*72 + ss]);
    uint4 w1 = *(const uint4*)(&T[d*72 + ss + 8]);
    unsigned short* dst = vt + ((size_t)((b*16 + h)*64 + d))*SEQ + s0 + ss;
    *(uint4*)dst = w0; *(uint4*)(dst + 8) = w1;
}

// ---------------------------------------------------------------------------
// MFMA flash attention, SWAPPED operands: S^T = mfma(K,Q), O^T = mfma(V^T,P^T).
// Each lane owns one q-row per mf (q = mf*16 + fr) -> lane-local softmax
// (2 shfl_xor only), per-lane scalar m/l state, b64 P writes, defer-max.
// 4 waves, QBLK=128 (32 q-rows/wave), KVBLK=64, double-buffered K/Vt.
// ---------------------------------------------------------------------------
__global__ __launch_bounds__(256) void attn_mfma(
    const unsigned short* __restrict__ qkvb,
    const unsigned short* __restrict__ vt,
    unsigned short* __restrict__ ctxb)
{
    __shared__ __align__(16) char pool[51200];
    unsigned short* Kb0 = (unsigned short*)pool;   // K0 K1 V0 V1: [64][64] each
    unsigned short* Vb0 = Kb0 + 8192;
    unsigned short* Pl  = Kb0 + 16384;             // 4 x [32][72]

    const int tid = threadIdx.x, w = tid >> 6, l = tid & 63;
    const int fr = l & 15, fq = l >> 4;
    const int b = blockIdx.z, h = blockIdx.y;
    const int q0 = blockIdx.x * 128;
    const int wq = q0 + w*32;

    const unsigned short* qb = qkvb + (size_t)b*SEQ*3072 + h*64;
    const unsigned short* kb = qb + 1024;
    const unsigned short* vb = vt + (size_t)((b*16 + h)*64)*SEQ;

    // Q fragments in registers for the whole KV loop (B-operand of S^T mfma)
    short8 qf[2][2];
#pragma unroll
    for (int mf = 0; mf < 2; ++mf)
#pragma unroll
        for (int kk = 0; kk < 2; ++kk)
            qf[mf][kk] = *(const short8*)(qb + (size_t)(wq + mf*16 + fr)*3072
                                          + kk*32 + fq*8);

    f32x4 o[2][4];                       // o[mf][df][r]: q=mf*16+fr, d=df*16+fq*4+r
    float mrun[2], lrun[2];              // per-lane: one q-row per mf
#pragma unroll
    for (int mf = 0; mf < 2; ++mf)
#pragma unroll
        for (int df = 0; df < 4; ++df)
#pragma unroll
            for (int r = 0; r < 4; ++r) o[mf][df][r] = 0.f;
    mrun[0] = mrun[1] = -1e30f;
    lrun[0] = lrun[1] = 0.f;

    const int srA = (w*2 + 0)*8 + (l >> 3);
    const int srB = (w*2 + 1)*8 + (l >> 3);
    const int scz = ((l & 7) ^ (l >> 3)) * 8;          // swizzled source col
    unsigned short* Pw = Pl + w*2304;

    const int c0e = (fq ^ (fr & 7)) * 8;               // swizzled frag read
    const int c1e = c0e ^ 32;

    auto stage = [&](int kv0, int buf) {
        unsigned short* Kd = Kb0 + buf*4096;
        unsigned short* Vd = Vb0 + buf*4096;
        gl16(kb + (size_t)(kv0 + srA)*3072 + scz, Kd + (w*2 + 0)*512);
        gl16(kb + (size_t)(kv0 + srB)*3072 + scz, Kd + (w*2 + 1)*512);
        gl16(vb + (size_t)srA*SEQ + kv0 + scz,    Vd + (w*2 + 0)*512);
        gl16(vb + (size_t)srB*SEQ + kv0 + scz,    Vd + (w*2 + 1)*512);
    };

    stage(0, 0);
    for (int kv0 = 0; kv0 < SEQ; kv0 += 64) {
        const int buf = (kv0 >> 6) & 1;
        __syncthreads();                 // tile(kv0) DMA done; buf^1 free
        if (kv0 + 64 < SEQ) stage(kv0 + 64, buf ^ 1);

        const unsigned short* Kc = Kb0 + buf*4096;
        const unsigned short* Vc = Vb0 + buf*4096;

        // ---- S^T = K Q^T : s[mf][nf][r] = S[q=mf*16+fr][k=nf*16+fq*4+r] ----
        f32x4 s[2][4];
#pragma unroll
        for (int mf = 0; mf < 2; ++mf)
#pragma unroll
            for (int nf = 0; nf < 4; ++nf)
#pragma unroll
                for (int r = 0; r < 4; ++r) s[mf][nf][r] = 0.f;
#pragma unroll
        for (int nf = 0; nf < 4; ++nf) {
            const short8 k0f = *(const short8*)(Kc + (nf*16 + fr)*64 + c0e);
            const short8 k1f = *(const short8*)(Kc + (nf*16 + fr)*64 + c1e);
#pragma unroll
            for (int mf = 0; mf < 2; ++mf) {
                s[mf][nf] = __builtin_amdgcn_mfma_f32_16x16x32_bf16(k0f, qf[mf][0], s[mf][nf], 0,0,0);
                s[mf][nf] = __builtin_amdgcn_mfma_f32_16x16x32_bf16(k1f, qf[mf][1], s[mf][nf], 0,0,0);
            }
        }

        // ---- softmax: lane-local fold + 2 shfl_xor; defer-max rescale ----
        float mx[2];
#pragma unroll
        for (int mf = 0; mf < 2; ++mf) {
            float a = fmaxf(fmaxf(s[mf][0][0], s[mf][0][1]), fmaxf(s[mf][0][2], s[mf][0][3]));
            float bb= fmaxf(fmaxf(s[mf][1][0], s[mf][1][1]), fmaxf(s[mf][1][2], s[mf][1][3]));
            float c = fmaxf(fmaxf(s[mf][2][0], s[mf][2][1]), fmaxf(s[mf][2][2], s[mf][2][3]));
            float d = fmaxf(fmaxf(s[mf][3][0], s[mf][3][1]), fmaxf(s[mf][3][2], s[mf][3][3]));
            float m = fmaxf(fmaxf(a, bb), fmaxf(c, d));
            m = fmaxf(m, __shfl_xor(m, 16));
            m = fmaxf(m, __shfl_xor(m, 32));
            mx[mf] = m;
        }
        const bool grow = (mx[0] > mrun[0] + THR_RAW) | (mx[1] > mrun[1] + THR_RAW);
        if (__any(grow)) {
#pragma unroll
            for (int mf = 0; mf < 2; ++mf) {
                const float mnew = fmaxf(mrun[mf], mx[mf]);
                const float corr = exp2f((mrun[mf] - mnew) * SC2);
                mrun[mf] = mnew;
                lrun[mf] *= corr;
#pragma unroll
                for (int df = 0; df < 4; ++df)
#pragma unroll
                    for (int r = 0; r < 4; ++r) o[mf][df][r] *= corr;
            }
        }
#pragma unroll
        for (int mf = 0; mf < 2; ++mf) {
            const float mb = mrun[mf] * SC2;
            float psum = 0.f;
#pragma unroll
            for (int nf = 0; nf < 4; ++nf) {
                const float p0 = exp2f(__builtin_fmaf(s[mf][nf][0], SC2, -mb));
                const float p1 = exp2f(__builtin_fmaf(s[mf][nf][1], SC2, -mb));
                const float p2 = exp2f(__builtin_fmaf(s[mf][nf][2], SC2, -mb));
                const float p3 = exp2f(__builtin_fmaf(s[mf][nf][3], SC2, -mb));
                psum += (p0 + p1) + (p2 + p3);
                unsigned u0, u1;
                asm("v_cvt_pk_bf16_f32 %0, %1, %2" : "=v"(u0) : "v"(p0), "v"(p1));
                asm("v_cvt_pk_bf16_f32 %0, %1, %2" : "=v"(u1) : "v"(p2), "v"(p3));
                *(unsigned long long*)(Pw + (mf*16 + fr)*72 + nf*16 + fq*4) =
                    (unsigned long long)u0 | ((unsigned long long)u1 << 32);
            }
            psum += __shfl_xor(psum, 16);
            psum += __shfl_xor(psum, 32);
            lrun[mf] += psum;
        }

        // ---- O^T += V^T P^T  (P wave-local; compiler orders ds write->read) ----
        short8 pa[2][2];
#pragma unroll
        for (int mf = 0; mf < 2; ++mf)
#pragma unroll
            for (int kk = 0; kk < 2; ++kk)
                pa[mf][kk] = *(const short8*)(Pw + (mf*16 + fr)*72 + kk*32 + fq*8);
#pragma unroll
        for (int df = 0; df < 4; ++df) {
            const short8 v0f = *(const short8*)(Vc + (df*16 + fr)*64 + c0e);
            const short8 v1f = *(const short8*)(Vc + (df*16 + fr)*64 + c1e);
#pragma unroll
            for (int mf = 0; mf < 2; ++mf) {
                o[mf][df] = __builtin_amdgcn_mfma_f32_16x16x32_bf16(v0f, pa[mf][0], o[mf][df], 0,0,0);
                o[mf][df] = __builtin_amdgcn_mfma_f32_16x16x32_bf16(v1f, pa[mf][1], o[mf][df], 0,0,0);
            }
        }
    }

    // ---- normalize + coalesced store via per-wave LDS repack ----
    __syncthreads();
    float* rp = (float*)(pool + w*8704);   // [32][68] f32
    const float inv0 = 1.f / lrun[0], inv1 = 1.f / lrun[1];
#pragma unroll
    for (int df = 0; df < 4; ++df) {
        f32x4 v0 = o[0][df] * inv0;
        f32x4 v1 = o[1][df] * inv1;
        *(f32x4*)&rp[(fr)*68      + df*16 + fq*4] = v0;
        *(f32x4*)&rp[(16 + fr)*68 + df*16 + fq*4] = v1;
    }
    const int orow = l >> 1, oc = (l & 1)*32;
    float vr[32];
#pragma unroll
    for (int j = 0; j < 8; ++j)
        *(f32x4*)&vr[j*4] = *(const f32x4*)&rp[orow*68 + oc + j*4];
    union { unsigned short s[32]; uint4 u[4]; } pk;
#pragma unroll
    for (int j = 0; j < 32; ++j) pk.s[j] = f2bf(vr[j]);
    unsigned short* dst = ctxb + (size_t)(b*SEQ + q0 + w*32 + orow)*DIMC + h*64 + oc;
#pragma unroll
    for (int j = 0; j < 4; ++j) *((uint4*)dst + j) = pk.u[j];
}

} // namespace

extern "C" void kernel_launch(void* const* d_in, const int* in_sizes, int n_in,
                              void* d_out, int out_size, void* d_ws, size_t ws_size,
                              hipStream_t stream)
{
    const float* x     = (const float*)d_in[0];
    const float* qkv_w = (const float*)d_in[1];
    const float* qkv_b = (const float*)d_in[2];
    const float* out_w = (const float*)d_in[3];
    const float* out_b = (const float*)d_in[4];

    // workspace carve (bf16 buffers), ~109 MB total
    unsigned short* xb   = (unsigned short*)d_ws;              // [8192][1024]
    unsigned short* wqb  = xb   + (size_t)8192*1024;           // [3072][1024]
    unsigned short* wob  = wqb  + (size_t)3072*1024;           // [1024][1024]
    unsigned short* qkvb = wob  + (size_t)1024*1024;           // [8192][3072]
    unsigned short* vtw  = qkvb + (size_t)8192*3072;           // [4096][2048]
    unsigned short* ctxb = vtw  + (size_t)4096*2048;           // [8192][1024]

    // 1) fp32 -> bf16 conversions
    cvt_f32_bf16<<<2048, 256, 0, stream>>>(x,     xb,  8192*1024/8);
    cvt_f32_bf16<<<1024, 256, 0, stream>>>(qkv_w, wqb, 3072*1024/8);
    cvt_f32_bf16<<<512,  256, 0, stream>>>(out_w, wob, 1024*1024/8);

    // 2) QKV projection (bf16 out): [8192,1024]x[3072,1024]^T
    gemm_bf16_mfma<1><<<dim3(24, 64), 256, 0, stream>>>(
        xb, wqb, qkv_b, (void*)qkvb, 8192, 3072, 1024);

    // 3) V transpose for PV's A-operand
    transpose_v<<<dim3(SEQ/64, HEADS, BATCH), 256, 0, stream>>>(qkvb, vtw);

    // 4) flash attention (bf16 MFMA, swapped operands) -> ctx bf16
    attn_mfma<<<dim3(SEQ/128, HEADS, BATCH), 256, 0, stream>>>(qkvb, vtw, ctxb);

    // 5) output projection (f32 out): [8192,1024]x[1024,1024]^T + bias
    gemm_bf16_mfma<0><<<dim3(8, 64), 256, 0, stream>>>(
        ctxb, wob, out_b, d_out, 8192, 1024, 1024);
}